// Round 9
// baseline (67.579 us; speedup 1.0000x reference)
//
#include <hip/hip_runtime.h>

// ---------------------------------------------------------------------------
// TimeLSTMCell fused kernel for MI355X (gfx950) — round 11
// B=4096, D=256, U=512; out = concat(h, c_m) fp32
//
// ROUND 11: prep shrunk to B-only; A converted in-kernel.
//   Nine rounds bracket the main loop (all levers flat ~33.5 +-1.5) -> the
//   remaining fat is prep (2240 blocks, 27MB) + ws round-trip.
//   - A-tiles (x,h0) are k-major already (no transpose): main stages them
//     directly: global float4 loads (issued at stage time) -> f2bf (same
//     RNE bit-twiddle as prep, bit-identical results) -> swizzled
//     ds_write_b128 AFTER compute (T14 async-split: HBM/L2 latency hides
//     under the MFMA phase). Write-side banks: 64 lanes = 8 rows x 128B ->
//     every bank 2x = free (m136).
//   - B keeps gl16 staging from prep'd transposed tiles (ksw/rsw).
//   - prep: B-only, 704 blocks (81920 kernel-chunks + 98304 rk-chunks).
//   - base structure = r4/r6 measured-best: 128x32 tile, 4 waves (2x2 of
//     64r x 16c), BK=64, dbuf 72KB LDS, 2 blocks/CU, plain-drain loop.
//   - epilogue: tanhfast + NEG_EPS constant fold (validated r9).
// ---------------------------------------------------------------------------

typedef __attribute__((ext_vector_type(8))) short short8_t;   // 8 bf16
typedef __attribute__((ext_vector_type(4))) float f32x4_t;
typedef unsigned int u32;

#define B_N 4096
#define D_K 256
#define U_N 512

__device__ __forceinline__ unsigned short f2bf(float f) {
    unsigned int x = __float_as_uint(f);
    unsigned int r = x + 0x7fffu + ((x >> 16) & 1u);   // RNE
    return (unsigned short)(r >> 16);
}

__device__ __forceinline__ float sigf(float z) {
    return 1.0f / (1.0f + __expf(-z));
}

// fast tanh: exact at +/-inf, ~1e-7 abs err
__device__ __forceinline__ float tanhfast(float z) {
    return 1.0f - 2.0f / (1.0f + __expf(2.0f * z));
}

__device__ __forceinline__ void gl16(const unsigned short* g, unsigned short* l) {
    __builtin_amdgcn_global_load_lds(
        (const __attribute__((address_space(1))) u32*)g,
        (__attribute__((address_space(3))) u32*)l, 16, 0, 0);
}

// swizzled element offset of (row r, k-chunk kc) inside a tile with 8 chunks/row
#define SWZ(r, kc) ((((r) * 8) + ((kc) ^ ((r) & 7))) * 8)

// ---------------------------------------------------------------------------
// prepass (B-only): 704 blocks x 256 = 180224 chunks (16B bf16 chunk each)
//   ker:  81920 chunks -> tiles (nb 0..15, kb 0..3) of 160x64 (transposed)
//   rk :  98304 chunks -> tiles (nb 0..15, kb 0..7) of  96x64 (transposed)
// ---------------------------------------------------------------------------
__global__ __launch_bounds__(256) void prep(
    const float* __restrict__ kern, const float* __restrict__ rk,
    unsigned short* __restrict__ ksw, unsigned short* __restrict__ rsw)
{
    const int c = blockIdx.x * 256 + threadIdx.x;
    if (c < 81920) {                        // ---- kernel (transpose) ----
        const int t = c / 1280, q = c - t * 1280;
        const int kc = q / 160, r = q - kc * 160;     // r = mat*32 + cc
        const int nb = t >> 2, kb = t & 3;
        const int col = (r >> 5) * U_N + nb * 32 + (r & 31);
        short8_t o;
#pragma unroll
        for (int j = 0; j < 8; ++j)
            o[j] = (short)f2bf(kern[(size_t)(kb * 64 + kc * 8 + j) * 2560 + col]);
        *reinterpret_cast<short8_t*>(ksw + (size_t)t * 10240 + SWZ(r, kc)) = o;
    } else {                                // ---- rk (transpose) ----
        const int c2 = c - 81920;
        const int t = c2 / 768, q = c2 - t * 768;
        const int kc = q / 96, r = q - kc * 96;       // r = mat*32 + cc
        const int nb = t >> 3, kb = t & 7;
        const int col = (r >> 5) * U_N + nb * 32 + (r & 31);
        short8_t o;
#pragma unroll
        for (int j = 0; j < 8; ++j)
            o[j] = (short)f2bf(rk[(size_t)(kb * 64 + kc * 8 + j) * 1536 + col]);
        *reinterpret_cast<short8_t*>(rsw + (size_t)t * 6144 + SWZ(r, kc)) = o;
    }
}

// ---------------------------------------------------------------------------
// main fused kernel
// grid (16, 32) = 512 blocks (2/CU), 256 threads (4 waves)
// wave (wm,wn) = (wave>>1, wave&1) owns rows [64*wm,+64) x cols [16*wn,+16)
// of the 128x32 band, for every stacked gate matrix.
// A staged in-kernel: fp32 global loads (issued with stage) -> f2bf ->
// swizzled ds_write (after compute); B staged via gl16 from prep'd tiles.
// ---------------------------------------------------------------------------
__global__ __launch_bounds__(256, 2) void tlstm_main(
    const float* __restrict__ x,              // [4096][256]  fp32 A src
    const float* __restrict__ h0,             // [4096][512]  fp32 A src
    const unsigned short* __restrict__ ksw,   // swizzled kernel^T tiles
    const unsigned short* __restrict__ rsw,   // swizzled rk^T tiles
    const float* __restrict__ tvec,           // [4096]
    const float* __restrict__ c0,             // [4096][512]
    const float* __restrict__ ktime,          // [1536] cols [t1,t2,o]
    float* __restrict__ out)                  // h, then c_m
{
    // per buffer: A 8192 elems (16KB) + B 10240 elems (20KB) = 36KB; x2 = 72KB
    __shared__ __align__(16) unsigned short lds[2][18432];

    const int tid = threadIdx.x;
    const int wave = tid >> 6;
    const int lane = tid & 63;
    const int lr = lane & 15;
    const int lq = lane >> 4;
    const int wm = wave >> 1;                 // 0..1 : row half
    const int wn = wave & 1;                  // 0..1 : col half
    const int nb = blockIdx.x;
    const int rb = blockIdx.y;

    // acc[m][p]: gate m (0..4 = x@K gates, 5..7 = h0@RK gates),
    // row-fragment p (rows wm*64 + p*16), cols wn*16..+16
    f32x4_t acc[8][4];
#pragma unroll
    for (int m = 0; m < 8; ++m)
#pragma unroll
        for (int p = 0; p < 4; ++p)
            acc[m][p] = (f32x4_t){0.f, 0.f, 0.f, 0.f};

    // ---- A staging registers: 4 chunks/thread x 8 floats (32 VGPR) ----
    f32x4_t va[4][2];

    // issue fp32 loads for A tile s (x for s<4, h0 for s>=4); coalesced:
    // lanes 0..7 cover one row's 64B..; chunk c=j*256+tid -> row=c>>3, kc=c&7
    auto loadA = [&](int s) {
        const float* base;
        int ld, kb;
        if (s < 4) { base = x  + (size_t)rb * 128 * D_K; ld = D_K; kb = s; }
        else       { base = h0 + (size_t)rb * 128 * U_N; ld = U_N; kb = s - 4; }
#pragma unroll
        for (int j = 0; j < 4; ++j) {
            const int c = j * 256 + tid, row = c >> 3, kc = c & 7;
            const float* p = base + (size_t)row * ld + kb * 64 + kc * 8;
            va[j][0] = *reinterpret_cast<const f32x4_t*>(p);
            va[j][1] = *reinterpret_cast<const f32x4_t*>(p + 4);
        }
    };

    // convert + swizzled ds_write of the tile loaded by the last loadA
    auto writeA = [&](int buf) {
        unsigned short* ab = &lds[buf][0];
#pragma unroll
        for (int j = 0; j < 4; ++j) {
            const int c = j * 256 + tid, row = c >> 3, kc = c & 7;
            short8_t o;
#pragma unroll
            for (int e = 0; e < 4; ++e) {
                o[e]     = (short)f2bf(va[j][0][e]);
                o[4 + e] = (short)f2bf(va[j][1][e]);
            }
            *reinterpret_cast<short8_t*>(ab + SWZ(row, kc)) = o;
        }
    };

    // B staging: linear global_load_lds (unchanged)
    auto stageB = [&](int s, int buf) {
        unsigned short* bb = &lds[buf][8192];
        if (s < 4) {
            const unsigned short* bt = ksw + (size_t)(nb * 4 + s) * 10240;
#pragma unroll
            for (int j = 0; j < 5; ++j)
                gl16(bt + (j * 256 + tid) * 8, bb + (j * 256 + wave * 64) * 8);
        } else {
            const unsigned short* bt = rsw + (size_t)(nb * 8 + (s - 4)) * 6144;
#pragma unroll
            for (int j = 0; j < 3; ++j)
                gl16(bt + (j * 256 + tid) * 8, bb + (j * 256 + wave * 64) * 8);
        }
    };

    auto compute1 = [&](int buf) {      // x @ kernel -> acc[0..4]
        const unsigned short* ab = &lds[buf][0];
        const unsigned short* bb = &lds[buf][8192];
#pragma unroll
        for (int ks = 0; ks < 2; ++ks) {
            const int kc = ks * 4 + lq;
            short8_t a[4];
#pragma unroll
            for (int p = 0; p < 4; ++p)
                a[p] = *reinterpret_cast<const short8_t*>(ab + SWZ(wm * 64 + p * 16 + lr, kc));
#pragma unroll
            for (int m = 0; m < 5; ++m) {
                const int r = m * 32 + wn * 16 + lr;
                short8_t b = *reinterpret_cast<const short8_t*>(bb + SWZ(r, kc));
#pragma unroll
                for (int p = 0; p < 4; ++p)
                    acc[m][p] = __builtin_amdgcn_mfma_f32_16x16x32_bf16(a[p], b, acc[m][p], 0, 0, 0);
            }
        }
    };

    auto compute2 = [&](int buf) {      // h0 @ rk -> acc[5..7]
        const unsigned short* ab = &lds[buf][0];
        const unsigned short* bb = &lds[buf][8192];
#pragma unroll
        for (int ks = 0; ks < 2; ++ks) {
            const int kc = ks * 4 + lq;
            short8_t a[4];
#pragma unroll
            for (int p = 0; p < 4; ++p)
                a[p] = *reinterpret_cast<const short8_t*>(ab + SWZ(wm * 64 + p * 16 + lr, kc));
#pragma unroll
            for (int m = 0; m < 3; ++m) {
                const int r = m * 32 + wn * 16 + lr;
                short8_t b = *reinterpret_cast<const short8_t*>(bb + SWZ(r, kc));
#pragma unroll
                for (int p = 0; p < 4; ++p)
                    acc[5 + m][p] = __builtin_amdgcn_mfma_f32_16x16x32_bf16(a[p], b, acc[5 + m][p], 0, 0, 0);
            }
        }
    };

    // ---- pipelined K-loop: 12 steps ----
    // step s: issue loads for tile s+1 (A->regs, B->LDS buf^1), compute tile
    // s, then cvt+ds_write A(s+1) (compiler waits the A-load regs here, i.e.
    // the HBM/L2 latency hid under compute), then barrier-drain.
    loadA(0); stageB(0, 0); writeA(0);
    __syncthreads();
    int cur = 0;
#pragma unroll 1
    for (int s = 0; s < 12; ++s) {
        if (s < 11) { loadA(s + 1); stageB(s + 1, cur ^ 1); }
        if (s < 4) compute1(cur); else compute2(cur);
        if (s < 11) writeA(cur ^ 1);
        __syncthreads();
        cur ^= 1;
    }

    // ---- epilogue: TimeLSTM elementwise (fp32) ----
    // t1_constraint: sigmoid output is always > -1e-5 -> constant -1e-5.
    const float NEG_EPS = -1e-5f;
    const int u = nb * 32 + wn * 16 + lr;
    const float kt1 = ktime[u];
    const float kt2 = ktime[U_N + u];
    const float kto = ktime[2 * U_N + u];
#pragma unroll
    for (int p = 0; p < 4; ++p)
#pragma unroll
        for (int i2 = 0; i2 < 4; ++i2) {
            const int b = rb * 128 + wm * 64 + p * 16 + lq * 4 + i2;
            const float tb = tvec[b];
            const float c0v = c0[(size_t)b * U_N + u];
            const float x_i  = acc[0][p][i2];
            const float x_c  = acc[1][p][i2];
            const float x_o  = acc[2][p][i2];
            const float x_t1 = acc[3][p][i2];
            const float x_t2 = acc[4][p][i2];
            const float r_i  = acc[5][p][i2];
            const float r_c  = acc[6][p][i2];
            const float r_o  = acc[7][p][i2];

            const float ig  = sigf(x_i + r_i);
            const float t1v = sigf(x_t1 + sigf(tb * kt1));
            const float t2v = sigf(x_t2 + sigf(tb * kt2));
            const float ct  = tanhfast(x_c + r_c);
            const float cm_ = (1.f - ig * t1v) * c0v + ig * ct * NEG_EPS;
            const float cm  = (1.f - ig) * c0v + ig * ct * t2v;
            const float og  = sigf(x_o + r_o + tb * kto);

            out[(size_t)b * U_N + u] = tanhfast(cm_) * og;
            out[(size_t)B_N * U_N + (size_t)b * U_N + u] = cm;
        }
}

// ---------------------------------------------------------------------------
extern "C" void kernel_launch(void* const* d_in, const int* in_sizes, int n_in,
                              void* d_out, int out_size, void* d_ws, size_t ws_size,
                              hipStream_t stream) {
    const float* x     = (const float*)d_in[0];   // [4096][256]
    const float* t     = (const float*)d_in[1];   // [4096][1]
    const float* h0    = (const float*)d_in[2];   // [4096][512]
    const float* c0    = (const float*)d_in[3];   // [4096][512]
    const float* kern  = (const float*)d_in[4];   // [256][2560]
    const float* rk    = (const float*)d_in[5];   // [512][1536]
    const float* ktime = (const float*)d_in[6];   // [1][1536]
    float* out = (float*)d_out;

    // ws layout (bytes) — B tiles only now (offsets kept from prior rounds):
    //   ksw @ 6291456  : 2560*256*2  = 1,310,720  (swizzled 160x64 tiles)
    //   rsw @ 7602176  : 1536*512*2  = 1,572,864  (swizzled  96x64 tiles)
    unsigned short* ksw = (unsigned short*)((char*)d_ws + 6291456);
    unsigned short* rsw = (unsigned short*)((char*)d_ws + 7602176);

    prep<<<704, 256, 0, stream>>>(kern, rk, ksw, rsw);
    tlstm_main<<<dim3(16, 32), 256, 0, stream>>>(
        x, h0, ksw, rsw, t, c0, ktime, out);
}